// Round 12
// baseline (518.382 us; speedup 1.0000x reference)
//
#include <hip/hip_runtime.h>

#define BATCH 4096
#define IN_DIM 1024
#define HID 16384
#define KTOP 64
#define KAUX 512
#define KSPLIT 4
#define LN_EPS 1e-5f
#define TIE_CAP 768
#define NBIN 2048

typedef short s16x8 __attribute__((ext_vector_type(8)));
typedef float f32x4 __attribute__((ext_vector_type(4)));

__device__ __forceinline__ ushort f2bf(float f) {
  unsigned u = __float_as_uint(f);
  u += 0x7FFFu + ((u >> 16) & 1u);   // RNE
  return (ushort)(u >> 16);
}
__device__ __forceinline__ float bf2f(ushort h) {
  return __uint_as_float(((unsigned)h) << 16);
}

__device__ __forceinline__ void gl_lds16(const void* g, void* l) {
  __builtin_amdgcn_global_load_lds(
      (const __attribute__((address_space(1))) unsigned*)g,
      (__attribute__((address_space(3))) unsigned*)l, 16, 0, 0);
}

#define BARRIER() do { __builtin_amdgcn_s_barrier(); asm volatile("" ::: "memory"); } while (0)

__device__ __forceinline__ float block_sum_f(float v) {
  __shared__ float redf[4];
  for (int o = 32; o > 0; o >>= 1) v += __shfl_down(v, o, 64);
  int lane = threadIdx.x & 63, w = threadIdx.x >> 6;
  if (lane == 0) redf[w] = v;
  __syncthreads();
  float t = (redf[0] + redf[1]) + (redf[2] + redf[3]);
  __syncthreads();
  return t;
}

__device__ __forceinline__ int block_sum_i(int v) {
  __shared__ int redi[4];
  for (int o = 32; o > 0; o >>= 1) v += __shfl_down(v, o, 64);
  int lane = threadIdx.x & 63, w = threadIdx.x >> 6;
  if (lane == 0) redi[w] = v;
  __syncthreads();
  int t = (redi[0] + redi[1]) + (redi[2] + redi[3]);
  __syncthreads();
  return t;
}

// ---------------- LayerNorm -> x_norm bf16, mu, std ----------------
__global__ __launch_bounds__(256) void ln_kernel(
    const float* __restrict__ x, const float* __restrict__ b_pre,
    ushort* __restrict__ xh, float* __restrict__ mu, float* __restrict__ stdv)
{
  int r = blockIdx.x, t = threadIdx.x;
  float4 v = ((const float4*)(x + (size_t)r * IN_DIM))[t];
  float s = (v.x + v.y) + (v.z + v.w);
  float mean = block_sum_f(s) * (1.0f / IN_DIM);
  float dx = v.x - mean, dy = v.y - mean, dz = v.z - mean, dw = v.w - mean;
  float ss = (dx*dx + dy*dy) + (dz*dz + dw*dw);
  float var = block_sum_f(ss) * (1.0f / (IN_DIM - 1));   // ddof = 1
  float sd = sqrtf(var);
  float inv = 1.0f / (sd + LN_EPS);
  float4 bp = ((const float4*)b_pre)[t];
  ushort h0 = f2bf(dx*inv - bp.x), h1 = f2bf(dy*inv - bp.y);
  ushort h2 = f2bf(dz*inv - bp.z), h3 = f2bf(dw*inv - bp.w);
  *(ushort4*)(xh + (size_t)r * IN_DIM + t * 4) = make_ushort4(h0, h1, h2, h3);
  if (t == 0) { mu[r] = mean; stdv[r] = sd; }
}

// ------- fused transposes: blocks [0,16384) -> w_enc; [16384,32768) -> w_dec ------
__global__ __launch_bounds__(256) void transpose2_k(
    const float* __restrict__ w_enc, ushort* __restrict__ wencT,
    const float* __restrict__ w_dec, ushort* __restrict__ wdecT,
    ushort* __restrict__ wdecB)
{
  __shared__ float tile[32][33];
  int id = blockIdx.x;
  const float* in; ushort* oh; ushort* orow; int R, C, bx, by;
  if (id < 16384) {
    in = w_enc; oh = wencT; orow = nullptr; R = IN_DIM; C = HID;
    bx = id & 511; by = id >> 9;
  } else {
    id -= 16384;
    in = w_dec; oh = wdecT; orow = wdecB; R = HID; C = IN_DIM;
    bx = id & 31; by = id >> 5;
  }
  int c0 = bx * 32, r0 = by * 32;
  int t = threadIdx.x;
  int col = t & 31, rbase = t >> 5;
  #pragma unroll
  for (int rep = 0; rep < 4; ++rep) {
    int rr = rbase + rep * 8;
    float v = in[(size_t)(r0 + rr) * C + c0 + col];
    tile[rr][col] = v;
    if (orow) orow[(size_t)(r0 + rr) * C + c0 + col] = f2bf(v);
  }
  __syncthreads();
  int j = t & 31, ibase = t >> 5;
  #pragma unroll
  for (int rep = 0; rep < 4; ++rep) {
    int i = ibase + rep * 8;
    oh[(size_t)(c0 + i) * R + r0 + j] = f2bf(tile[j][i]);
  }
}

// ---- frag-read / MFMA helpers (compile-time indices only — rule #20) ----
#define RD_A4(DST, PA, MI0)                                                     \
  _Pragma("unroll")                                                             \
  for (int ks = 0; ks < 2; ++ks)                                                \
    _Pragma("unroll")                                                           \
    for (int i = 0; i < 4; ++i)                                                 \
      DST[ks][i] = *(const s16x8*)&PA[(wm * 128 + ((MI0) + i) * 16 + fr) * 64 + \
                                      (((ks * 4 + fq) ^ axr) * 8)];

#define RD_B2(DST, PB, NI0)                                                     \
  _Pragma("unroll")                                                             \
  for (int ks = 0; ks < 2; ++ks)                                                \
    _Pragma("unroll")                                                           \
    for (int n = 0; n < 2; ++n)                                                 \
      DST[ks][n] = *(const s16x8*)&PB[(wn * 64 + ((NI0) + n) * 16 + fr) * 64 +  \
                                      (((ks * 4 + fq) ^ axr) * 8)];

#define MFMA16(AF, BF, MI0, NI0)                                                \
  __builtin_amdgcn_s_setprio(1);                                                \
  _Pragma("unroll")                                                             \
  for (int ks = 0; ks < 2; ++ks)                                                \
    _Pragma("unroll")                                                           \
    for (int i = 0; i < 4; ++i)                                                 \
      _Pragma("unroll")                                                         \
      for (int n = 0; n < 2; ++n)                                               \
        acc[(MI0) + i][(NI0) + n] = __builtin_amdgcn_mfma_f32_16x16x32_bf16(    \
            AF[ks][i], BF[ks][n], acc[(MI0) + i][(NI0) + n], 0, 0, 0);          \
  __builtin_amdgcn_s_setprio(0);

// ---------------- GEMM C = A @ B^T, 256x256, 8-phase windows + counted vmcnt ------
// LDS: 2 buf x (A 256x64 | B 256x64) bf16 = 128 KiB. T2 both-sides XOR swizzle.
// MODE 0: Cb bf16 = f2bf(acc + bias[n])   (encoder; 2D-XCD map: XCD owns 8 bn x all bm)
// MODE 1: Cb bf16 partial (split-K via z)  (decoder)
template<int MODE>
__global__ __launch_bounds__(512, 2) void gemm256(
    const ushort* __restrict__ A, const ushort* __restrict__ B,
    ushort* __restrict__ Cb, const float* __restrict__ bias,
    int M, int N, int K, int kchunk)
{
  __shared__ ushort lds[2 * 2 * 256 * 64];

  const int tid = threadIdx.x;
  const int w = tid >> 6, lane = tid & 63;
  const int fr = lane & 15, fq = lane >> 4;
  const int wm = w >> 2, wn = w & 3;
  const int axr = fr & 7;

  int bn0, bm0;
  const int flat = blockIdx.y * gridDim.x + blockIdx.x;
  if constexpr (MODE == 0) {
    // XCD x (= flat&7) owns bn panels [8x,8x+8) x all bm tiles.
    const int x = flat & 7, k = flat >> 3;
    bn0 = (x * 8 + (k & 7)) * 256;
    bm0 = (k >> 3) * 256;
  } else {
    const int gx = gridDim.x, nwg = gx * gridDim.y;   // %8==0
    const int cpx = nwg >> 3;
    const int sw = (flat & 7) * cpx + (flat >> 3);
    bn0 = (sw % gx) * 256; bm0 = (sw / gx) * 256;
  }
  const int kbeg = blockIdx.z * kchunk;

  const int srow = tid >> 3, sslot = tid & 7;

  // stage half h of K-tile kt: h 0,1 = A rows [0,128)/[128,256); h 2,3 = B same.
  auto STAGE_HALF = [&](int kt, int h) {
    const int k0 = kbeg + (kt << 6);
    const int lb = (kt & 1) * 32768 + (h >> 1) * 16384;
    #pragma unroll
    for (int q = 0; q < 2; ++q) {
      int row = (h & 1) * 128 + q * 64 + srow;
      int gcol = (sslot ^ (row & 7)) * 8;
      const ushort* src = (h < 2) ? (A + (size_t)(bm0 + row) * K)
                                  : (B + (size_t)(bn0 + row) * K);
      gl_lds16(src + k0 + gcol, &lds[lb + row * 64 + sslot * 8]);
    }
  };

  f32x4 acc[8][4] = {};
  const int nt = kchunk >> 6;

  #pragma unroll
  for (int h = 0; h < 4; ++h) STAGE_HALF(0, h);

  s16x8 af03[2][4], af47[2][4], bf01[2][2], bf23[2][2];

  for (int t = 0; t < nt; ++t) {
    const ushort* Ab = &lds[(t & 1) * 32768];
    const ushort* Bb = Ab + 16384;
    const bool more = (t + 1 < nt);

    // ---- P0: stage h0,h1(next) early + counted vmcnt; then issue Q1 reads ----
    if (more) {
      STAGE_HALF(t + 1, 0);
      STAGE_HALF(t + 1, 1);
      asm volatile("s_waitcnt vmcnt(4)" ::: "memory");   // tile t fully resident
    } else {
      asm volatile("s_waitcnt vmcnt(0)" ::: "memory");
    }
    BARRIER();
    RD_A4(af03, Ab, 0);
    RD_B2(bf01, Bb, 0);
    BARRIER();
    // ---- P1: read bf23 | MFMA Q1 ----
    RD_B2(bf23, Bb, 2);
    MFMA16(af03, bf01, 0, 0);
    if (more) STAGE_HALF(t + 1, 2);
    BARRIER();
    // ---- P2: read af47 | MFMA Q2 ----
    RD_A4(af47, Ab, 4);
    MFMA16(af03, bf23, 0, 2);
    if (more) STAGE_HALF(t + 1, 3);
    BARRIER();
    // ---- P3: drain LDS reads, pure MFMA Q3+Q4 ----
    asm volatile("s_waitcnt lgkmcnt(0)" ::: "memory");
    __builtin_amdgcn_sched_barrier(0);                   // rule #18
    MFMA16(af47, bf01, 4, 0);
    MFMA16(af47, bf23, 4, 2);
  }

  #pragma unroll
  for (int mi = 0; mi < 8; ++mi) {
    int grow_b = bm0 + wm * 128 + mi * 16 + fq * 4;
    #pragma unroll
    for (int ni = 0; ni < 4; ++ni) {
      int gcol = bn0 + wn * 64 + ni * 16 + fr;
      #pragma unroll
      for (int q = 0; q < 4; ++q) {
        int grow = grow_b + q;
        if constexpr (MODE == 0) {
          Cb[(size_t)grow * N + gcol] = f2bf(acc[mi][ni][q] + bias[gcol]);
        } else {
          Cb[((size_t)blockIdx.z * M + grow) * N + gcol] = f2bf(acc[mi][ni][q]);
        }
      }
    }
  }
}

// ---------------- reduce split-K partials + decoder epilogue ----------------
__global__ __launch_bounds__(256) void reduce_dec(
    const ushort* __restrict__ P, const float* __restrict__ b_pre,
    const float* __restrict__ stdv, const float* __restrict__ muv,
    float* __restrict__ out)
{
  int gid = blockIdx.x * 256 + threadIdx.x;
  size_t e0 = (size_t)gid * 4;
  int r = (int)(e0 >> 10), c = (int)(e0 & 1023);
  float sx = 0.f, sy = 0.f, sz = 0.f, sw = 0.f;
  #pragma unroll
  for (int ks = 0; ks < KSPLIT; ++ks) {
    ushort4 p = *(const ushort4*)&P[(size_t)ks * BATCH * IN_DIM + e0];
    sx += bf2f(p.x); sy += bf2f(p.y); sz += bf2f(p.z); sw += bf2f(p.w);
  }
  float4 bp = *(const float4*)&b_pre[c];
  float s = stdv[r], m = muv[r];
  float4 o;
  o.x = (sx + bp.x) * s + m;
  o.y = (sy + bp.y) * s + m;
  o.z = (sz + bp.z) * s + m;
  o.w = (sw + bp.w) * s + m;
  *(float4*)&out[e0] = o;
}

// ---------------- top-k v4: bf16 keys, exact bf16 thresholds, in-place dense A2 ---
__device__ __forceinline__ void scan_find(int* hist, int t, int K1, int K2,
                                          int* res, int* wsum)
{
  int lane = t & 63, w = t >> 6;
  int h[8];
  #pragma unroll
  for (int j = 0; j < 8; ++j) h[j] = hist[t * 8 + j];
  int p = 0;
  #pragma unroll
  for (int j = 0; j < 8; ++j) p += h[j];
  int v = p;
  #pragma unroll
  for (int off = 1; off < 64; off <<= 1) {
    int o = __shfl_down(v, off, 64);
    if (lane + off < 64) v += o;
  }
  if (lane == 0) wsum[w] = v;
  __syncthreads();
  int above_w = 0;
  for (int ww = w + 1; ww < 4; ++ww) above_w += wsum[ww];
  int incl = v + above_w;
  int E = incl - p;                // suffix strictly above this thread's bins
  int S[9];
  S[8] = E;
  #pragma unroll
  for (int j = 7; j >= 0; --j) S[j] = h[j] + S[j + 1];
  #pragma unroll
  for (int j = 0; j < 8; ++j) {
    if (S[j] >= K1 && S[j + 1] < K1) { res[0] = t * 8 + j; res[1] = S[j + 1]; }
    if (S[j] >= K2 && S[j + 1] < K2) { res[2] = t * 8 + j; res[3] = S[j + 1]; }
  }
  __syncthreads();
}

// Reads A2 row r (= pre_acts) into registers, then overwrites it IN PLACE with the
// dense aux row (strict-greater values, zeros, ties patched). Block-local: safe.
__global__ __launch_bounds__(256) void topk4_kernel(
    ushort* __restrict__ A2,
    int* __restrict__ midx, float* __restrict__ mval,
    int* __restrict__ fired)
{
  const int r = blockIdx.x, t = threadIdx.x;
  ushort* A2row = A2 + (size_t)r * HID;
  __shared__ int histA[NBIN];
  __shared__ int histC[32], histD[32];
  __shared__ int wsum[4];
  __shared__ int res[8];
  __shared__ int tidx64[TIE_CAP], tidx512[TIE_CAP];
  __shared__ int cm, ca, c64, c512;

  // 64 bf16 keys per thread (sortable u16: sign? ~u : u|0x8000)
  ushort key[64];
  const uint4* src = (const uint4*)A2row;
  #pragma unroll
  for (int c = 0; c < 8; ++c) {
    uint4 u = src[c * 256 + t];
    unsigned uu[4] = {u.x, u.y, u.z, u.w};
    #pragma unroll
    for (int p = 0; p < 4; ++p) {
      ushort lo = (ushort)(uu[p] & 0xFFFFu), hi = (ushort)(uu[p] >> 16);
      key[c * 8 + p * 2]     = (lo & 0x8000) ? (ushort)(lo ^ 0xFFFF) : (ushort)(lo | 0x8000);
      key[c * 8 + p * 2 + 1] = (hi & 0x8000) ? (ushort)(hi ^ 0xFFFF) : (ushort)(hi | 0x8000);
    }
  }
  #pragma unroll
  for (int j = 0; j < 8; ++j) histA[t * 8 + j] = 0;
  if (t < 32) { histC[t] = 0; histD[t] = 0; }
  if (t == 0) { cm = 0; ca = 0; c64 = 0; c512 = 0; }
  __syncthreads();

  // level 1: bins = key >> 5 (2048)
  #pragma unroll
  for (int q = 0; q < 64; ++q) atomicAdd(&histA[key[q] >> 5], 1);
  __syncthreads();
  scan_find(histA, t, KTOP, KAUX, res, wsum);
  const int B64 = res[0], above64 = res[1], B512 = res[2], above512 = res[3];

  // level 2: 32 sub-bins within each boundary bin -> exact bf16 threshold
  #pragma unroll
  for (int q = 0; q < 64; ++q) {
    int k = key[q];
    if ((k >> 5) == B64)  atomicAdd(&histC[k & 31], 1);
    if ((k >> 5) == B512) atomicAdd(&histD[k & 31], 1);
  }
  __syncthreads();
  if (t == 0) {
    int need = KTOP - above64, s = 0, sub = 31;
    for (int j = 31; j >= 0; --j) { s += histC[j]; if (s >= need) { sub = j; break; } }
    res[4] = (B64 << 5) | sub;
  }
  if (t == 64) {
    int need = KAUX - above512, s = 0, sub = 31;
    for (int j = 31; j >= 0; --j) { s += histD[j]; if (s >= need) { sub = j; break; } }
    res[6] = (B512 << 5) | sub;
  }
  __syncthreads();
  const ushort T64 = (ushort)res[4], T512 = (ushort)res[6];

  // output pass: main -> midx/mval/fired; aux -> dense in-place row write
  #pragma unroll
  for (int c = 0; c < 8; ++c) {
    ushort w8[8];
    #pragma unroll
    for (int j = 0; j < 8; ++j) {
      ushort k = key[c * 8 + j];
      int i = c * 2048 + t * 8 + j;
      ushort wv = 0;
      if (k > T512) {
        wv = (k > 0x8000) ? (ushort)(k & 0x7FFF) : (ushort)0;
        atomicAdd(&ca, 1);
      } else if (k == T512) {
        int p = atomicAdd(&c512, 1);
        if (p < TIE_CAP) tidx512[p] = i;
      }
      w8[j] = wv;
      if (k > T64) {
        int p = atomicAdd(&cm, 1);
        midx[(size_t)r * KTOP + p] = i;
        mval[(size_t)r * KTOP + p] = (k > 0x8000) ? bf2f((ushort)(k & 0x7FFF)) : 0.f;
        if (k > 0x8000) fired[i] = 1;
      } else if (k == T64) {
        int p = atomicAdd(&c64, 1);
        if (p < TIE_CAP) tidx64[p] = i;
      }
    }
    uint4 uu;
    uu.x = (unsigned)w8[0] | ((unsigned)w8[1] << 16);
    uu.y = (unsigned)w8[2] | ((unsigned)w8[3] << 16);
    uu.z = (unsigned)w8[4] | ((unsigned)w8[5] << 16);
    uu.w = (unsigned)w8[6] | ((unsigned)w8[7] << 16);
    *(uint4*)(A2row + c * 2048 + t * 8) = uu;
  }
  __syncthreads();

  if (t == 0) {   // fill main with ties (all same value), lowest index first
    int have = cm, ntc = c64 < TIE_CAP ? c64 : TIE_CAP, need = KTOP - have;
    float rv = (T64 > 0x8000) ? bf2f((ushort)(T64 & 0x7FFF)) : 0.f;
    for (int q = 0; q < need; ++q) {
      int best = 0x7FFFFFFF, bi = -1;
      for (int u = 0; u < ntc; ++u) if (tidx64[u] < best) { best = tidx64[u]; bi = u; }
      if (bi < 0) break;
      tidx64[bi] = 0x7FFFFFFF;
      midx[(size_t)r * KTOP + have + q] = best;
      mval[(size_t)r * KTOP + have + q] = rv;
      if (T64 > 0x8000) fired[best] = 1;
    }
  }
  if (t == 64) {  // patch aux ties into the dense row, lowest index first
    int have = ca, ntc = c512 < TIE_CAP ? c512 : TIE_CAP, need = KAUX - have;
    ushort rb = (T512 > 0x8000) ? (ushort)(T512 & 0x7FFF) : (ushort)0;
    for (int q = 0; q < need; ++q) {
      int best = 0x7FFFFFFF, bi = -1;
      for (int u = 0; u < ntc; ++u) if (tidx512[u] < best) { best = tidx512[u]; bi = u; }
      if (bi < 0) break;
      tidx512[bi] = 0x7FFFFFFF;
      A2row[best] = rb;
    }
  }
}

// ---------------- stats / num_dead ----------------
__global__ __launch_bounds__(256) void stats_kernel(
    const int* __restrict__ fired, const int* __restrict__ sln, float* __restrict__ nd_out)
{
  int t = threadIdx.x, c = 0;
  for (int j = t; j < HID; j += 256) {
    int dead = (fired[j] == 0) ? 1 : 0;
    int stats = sln[j] * dead + 1;
    if ((float)stats > (2000.0f / 4096.0f)) c++;
  }
  c = block_sum_i(c);
  if (t == 0) nd_out[0] = (float)c;
}

// ---------------- main decode: sparse gather of bf16 w_dec, f32 accumulate --------
__global__ __launch_bounds__(256) void decode_main(
    const int* __restrict__ midx, const float* __restrict__ mval,
    const ushort* __restrict__ wdecB, const float* __restrict__ b_pre,
    const float* __restrict__ stdv, const float* __restrict__ muv,
    float* __restrict__ out)
{
  int r = blockIdx.x, t = threadIdx.x;
  __shared__ int sj[KTOP];
  __shared__ float sv[KTOP];
  if (t < KTOP) { sj[t] = midx[(size_t)r * KTOP + t]; sv[t] = mval[(size_t)r * KTOP + t]; }
  __syncthreads();
  float ax = 0.f, ay = 0.f, az = 0.f, aw = 0.f;
  #pragma unroll 8
  for (int i = 0; i < KTOP; ++i) {
    float v = sv[i];
    ushort4 wv = *(const ushort4*)(wdecB + (size_t)sj[i] * IN_DIM + t * 4);
    ax += v * bf2f(wv.x); ay += v * bf2f(wv.y);
    az += v * bf2f(wv.z); aw += v * bf2f(wv.w);
  }
  float4 bp = ((const float4*)b_pre)[t];
  float s = stdv[r], m = muv[r];
  float4 o;
  o.x = (ax + bp.x) * s + m;
  o.y = (ay + bp.y) * s + m;
  o.z = (az + bp.z) * s + m;
  o.w = (aw + bp.w) * s + m;
  ((float4*)(out + (size_t)r * IN_DIM))[t] = o;
}

__global__ void diag_kernel(float* p, float v) { p[0] = v; }

// ---------------- launch ----------------
extern "C" void kernel_launch(void* const* d_in, const int* in_sizes, int n_in,
                              void* d_out, int out_size, void* d_ws, size_t ws_size,
                              hipStream_t stream)
{
  const float* x     = (const float*)d_in[0];
  const float* w_enc = (const float*)d_in[1];
  const float* w_dec = (const float*)d_in[2];
  const float* b_enc = (const float*)d_in[3];
  const float* b_pre = (const float*)d_in[4];
  const int*   sln   = (const int*)d_in[5];

  float* out0 = (float*)d_out;                          // recons [4096][1024]
  float* out1 = out0 + (size_t)BATCH * IN_DIM;          // aux_recons
  float* out2 = out0 + 2 * (size_t)BATCH * IN_DIM;      // num_dead (as f32)

  char* ws = (char*)d_ws;
  size_t off = 0;
  auto take = [&](size_t bytes) { char* p = ws + off; off += (bytes + 255) & ~(size_t)255; return p; };

  // A2 (128 MB): encoder writes full-batch bf16 pre_acts here; topk4 converts each
  // row IN PLACE to the dense aux matrix.
  ushort* A2       = (ushort*)take((size_t)BATCH * HID * 2);
  // wencT (32 MB) is dead after the encoder -> reused as split-K partials (KSPLIT=4)
  ushort* wencT    = (ushort*)take((size_t)HID * IN_DIM * 2);
  ushort* part     = wencT;
  ushort* wdecB    = (ushort*)take((size_t)HID * IN_DIM * 2);
  ushort* wdecT    = (ushort*)take((size_t)HID * IN_DIM * 2);
  ushort* xh       = (ushort*)take((size_t)BATCH * IN_DIM * 2);
  float*  mu       = (float*)take(BATCH * 4);
  float*  stdv     = (float*)take(BATCH * 4);
  int*    midx     = (int*)take((size_t)BATCH * KTOP * 4);
  float*  mval     = (float*)take((size_t)BATCH * KTOP * 4);
  int*    fired    = (int*)take(HID * 4);

  if (ws_size < off) {  // diagnostic: report actual ws_size through num_dead slot
    diag_kernel<<<1, 1, 0, stream>>>(out2, (float)ws_size);
    return;
  }

  ln_kernel<<<BATCH, 256, 0, stream>>>(x, b_pre, xh, mu, stdv);
  transpose2_k<<<32768, 256, 0, stream>>>(w_enc, wencT, w_dec, wdecT, wdecB);
  hipMemsetAsync(fired, 0, HID * sizeof(int), stream);

  // full-batch encoder: grid (64,16) = 1024 blocks
  gemm256<0><<<dim3(HID / 256, BATCH / 256, 1), 512, 0, stream>>>(
      xh, wencT, A2, b_enc, BATCH, HID, IN_DIM, IN_DIM);
  // full-batch in-place top-k (pre row -> dense aux row)
  topk4_kernel<<<BATCH, 256, 0, stream>>>(A2, midx, mval, fired);
  stats_kernel<<<1, 256, 0, stream>>>(fired, sln, out2);

  // main decode: consumes wdecB (untouched later; part aliases wencT only)
  decode_main<<<BATCH, 256, 0, stream>>>(midx, mval, wdecB, b_pre, stdv, mu, out0);

  gemm256<1><<<dim3(IN_DIM / 256, BATCH / 256, KSPLIT), 512, 0, stream>>>(
      A2, wdecT, part, nullptr, BATCH, IN_DIM, HID, HID / KSPLIT);
  reduce_dec<<<(BATCH * IN_DIM) / 1024, 256, 0, stream>>>(part, b_pre, stdv, mu, out1);
}

// Round 13
// 513.992 us; speedup vs baseline: 1.0085x; 1.0085x over previous
//
#include <hip/hip_runtime.h>

#define BATCH 4096
#define IN_DIM 1024
#define HID 16384
#define KTOP 64
#define KAUX 512
#define KSPLIT 4
#define LN_EPS 1e-5f
#define TIE_CAP 768
#define NBIN 2048

typedef short s16x8 __attribute__((ext_vector_type(8)));
typedef float f32x4 __attribute__((ext_vector_type(4)));

__device__ __forceinline__ ushort f2bf(float f) {
  unsigned u = __float_as_uint(f);
  u += 0x7FFFu + ((u >> 16) & 1u);   // RNE
  return (ushort)(u >> 16);
}
__device__ __forceinline__ float bf2f(ushort h) {
  return __uint_as_float(((unsigned)h) << 16);
}

__device__ __forceinline__ void gl_lds16(const void* g, void* l) {
  __builtin_amdgcn_global_load_lds(
      (const __attribute__((address_space(1))) unsigned*)g,
      (__attribute__((address_space(3))) unsigned*)l, 16, 0, 0);
}

#define BARRIER() do { __builtin_amdgcn_s_barrier(); asm volatile("" ::: "memory"); } while (0)

__device__ __forceinline__ float block_sum_f(float v) {
  __shared__ float redf[4];
  for (int o = 32; o > 0; o >>= 1) v += __shfl_down(v, o, 64);
  int lane = threadIdx.x & 63, w = threadIdx.x >> 6;
  if (lane == 0) redf[w] = v;
  __syncthreads();
  float t = (redf[0] + redf[1]) + (redf[2] + redf[3]);
  __syncthreads();
  return t;
}

__device__ __forceinline__ int block_sum_i(int v) {
  __shared__ int redi[4];
  for (int o = 32; o > 0; o >>= 1) v += __shfl_down(v, o, 64);
  int lane = threadIdx.x & 63, w = threadIdx.x >> 6;
  if (lane == 0) redi[w] = v;
  __syncthreads();
  int t = (redi[0] + redi[1]) + (redi[2] + redi[3]);
  __syncthreads();
  return t;
}

// ---------------- fused prologue -----------------------------------------------
// blocks [0,4096):          LayerNorm row (blocks 0..15 also zero `fired`)
// blocks [4096,20480):      transpose w_enc -> wencT (bf16 [HID][IN_DIM])
// blocks [20480,36864):     transpose w_dec -> wdecT + row-major bf16 wdecB
__global__ __launch_bounds__(256) void prep_kernel(
    const float* __restrict__ x, const float* __restrict__ b_pre,
    ushort* __restrict__ xh, float* __restrict__ mu, float* __restrict__ stdv,
    const float* __restrict__ w_enc, ushort* __restrict__ wencT,
    const float* __restrict__ w_dec, ushort* __restrict__ wdecT,
    ushort* __restrict__ wdecB, int* __restrict__ fired)
{
  __shared__ float tile[32][33];
  int id = blockIdx.x;
  int t = threadIdx.x;

  if (id < BATCH) {
    // ---- LayerNorm ----
    if (id < 16) *(int4*)&fired[id * 1024 + t * 4] = make_int4(0, 0, 0, 0);
    int r = id;
    float4 v = ((const float4*)(x + (size_t)r * IN_DIM))[t];
    float s = (v.x + v.y) + (v.z + v.w);
    float mean = block_sum_f(s) * (1.0f / IN_DIM);
    float dx = v.x - mean, dy = v.y - mean, dz = v.z - mean, dw = v.w - mean;
    float ss = (dx*dx + dy*dy) + (dz*dz + dw*dw);
    float var = block_sum_f(ss) * (1.0f / (IN_DIM - 1));   // ddof = 1
    float sd = sqrtf(var);
    float inv = 1.0f / (sd + LN_EPS);
    float4 bp = ((const float4*)b_pre)[t];
    ushort h0 = f2bf(dx*inv - bp.x), h1 = f2bf(dy*inv - bp.y);
    ushort h2 = f2bf(dz*inv - bp.z), h3 = f2bf(dw*inv - bp.w);
    *(ushort4*)(xh + (size_t)r * IN_DIM + t * 4) = make_ushort4(h0, h1, h2, h3);
    if (t == 0) { mu[r] = mean; stdv[r] = sd; }
    return;
  }
  id -= BATCH;

  const float* in; ushort* oh; ushort* orow; int R, C, bx, by;
  if (id < 16384) {
    in = w_enc; oh = wencT; orow = nullptr; R = IN_DIM; C = HID;
    bx = id & 511; by = id >> 9;
  } else {
    id -= 16384;
    in = w_dec; oh = wdecT; orow = wdecB; R = HID; C = IN_DIM;
    bx = id & 31; by = id >> 5;
  }
  int c0 = bx * 32, r0 = by * 32;
  int col = t & 31, rbase = t >> 5;
  #pragma unroll
  for (int rep = 0; rep < 4; ++rep) {
    int rr = rbase + rep * 8;
    float v = in[(size_t)(r0 + rr) * C + c0 + col];
    tile[rr][col] = v;
    if (orow) orow[(size_t)(r0 + rr) * C + c0 + col] = f2bf(v);
  }
  __syncthreads();
  int j = t & 31, ibase = t >> 5;
  #pragma unroll
  for (int rep = 0; rep < 4; ++rep) {
    int i = ibase + rep * 8;
    oh[(size_t)(c0 + i) * R + r0 + j] = f2bf(tile[j][i]);
  }
}

// ---- frag-read / MFMA helpers (compile-time indices only — rule #20) ----
#define RD_A4(DST, PA, MI0)                                                     \
  _Pragma("unroll")                                                             \
  for (int ks = 0; ks < 2; ++ks)                                                \
    _Pragma("unroll")                                                           \
    for (int i = 0; i < 4; ++i)                                                 \
      DST[ks][i] = *(const s16x8*)&PA[(wm * 128 + ((MI0) + i) * 16 + fr) * 64 + \
                                      (((ks * 4 + fq) ^ axr) * 8)];

#define RD_B2(DST, PB, NI0)                                                     \
  _Pragma("unroll")                                                             \
  for (int ks = 0; ks < 2; ++ks)                                                \
    _Pragma("unroll")                                                           \
    for (int n = 0; n < 2; ++n)                                                 \
      DST[ks][n] = *(const s16x8*)&PB[(wn * 64 + ((NI0) + n) * 16 + fr) * 64 +  \
                                      (((ks * 4 + fq) ^ axr) * 8)];

#define MFMA16(AF, BF, MI0, NI0)                                                \
  __builtin_amdgcn_s_setprio(1);                                                \
  _Pragma("unroll")                                                             \
  for (int ks = 0; ks < 2; ++ks)                                                \
    _Pragma("unroll")                                                           \
    for (int i = 0; i < 4; ++i)                                                 \
      _Pragma("unroll")                                                         \
      for (int n = 0; n < 2; ++n)                                               \
        acc[(MI0) + i][(NI0) + n] = __builtin_amdgcn_mfma_f32_16x16x32_bf16(    \
            AF[ks][i], BF[ks][n], acc[(MI0) + i][(NI0) + n], 0, 0, 0);          \
  __builtin_amdgcn_s_setprio(0);

// ---------------- GEMM C = A @ B^T, 256x256, 8-phase windows + counted vmcnt ------
// LDS: 2 buf x (A 256x64 | B 256x64) bf16 = 128 KiB. T2 both-sides XOR swizzle.
// MODE 0: Cb bf16 = f2bf(acc + bias[n])   (encoder; 2D-XCD map: XCD owns 8 bn x all bm)
// MODE 1: Cb bf16 partial (split-K via z)  (decoder)
template<int MODE>
__global__ __launch_bounds__(512, 2) void gemm256(
    const ushort* __restrict__ A, const ushort* __restrict__ B,
    ushort* __restrict__ Cb, const float* __restrict__ bias,
    int M, int N, int K, int kchunk)
{
  __shared__ ushort lds[2 * 2 * 256 * 64];

  const int tid = threadIdx.x;
  const int w = tid >> 6, lane = tid & 63;
  const int fr = lane & 15, fq = lane >> 4;
  const int wm = w >> 2, wn = w & 3;
  const int axr = fr & 7;

  int bn0, bm0;
  const int flat = blockIdx.y * gridDim.x + blockIdx.x;
  if constexpr (MODE == 0) {
    // XCD x (= flat&7) owns bn panels [8x,8x+8) x all bm tiles.
    const int x = flat & 7, k = flat >> 3;
    bn0 = (x * 8 + (k & 7)) * 256;
    bm0 = (k >> 3) * 256;
  } else {
    const int gx = gridDim.x, nwg = gx * gridDim.y;   // %8==0
    const int cpx = nwg >> 3;
    const int sw = (flat & 7) * cpx + (flat >> 3);
    bn0 = (sw % gx) * 256; bm0 = (sw / gx) * 256;
  }
  const int kbeg = blockIdx.z * kchunk;

  const int srow = tid >> 3, sslot = tid & 7;

  // stage half h of K-tile kt: h 0,1 = A rows [0,128)/[128,256); h 2,3 = B same.
  auto STAGE_HALF = [&](int kt, int h) {
    const int k0 = kbeg + (kt << 6);
    const int lb = (kt & 1) * 32768 + (h >> 1) * 16384;
    #pragma unroll
    for (int q = 0; q < 2; ++q) {
      int row = (h & 1) * 128 + q * 64 + srow;
      int gcol = (sslot ^ (row & 7)) * 8;
      const ushort* src = (h < 2) ? (A + (size_t)(bm0 + row) * K)
                                  : (B + (size_t)(bn0 + row) * K);
      gl_lds16(src + k0 + gcol, &lds[lb + row * 64 + sslot * 8]);
    }
  };

  f32x4 acc[8][4] = {};
  const int nt = kchunk >> 6;

  #pragma unroll
  for (int h = 0; h < 4; ++h) STAGE_HALF(0, h);

  s16x8 af03[2][4], af47[2][4], bf01[2][2], bf23[2][2];

  for (int t = 0; t < nt; ++t) {
    const ushort* Ab = &lds[(t & 1) * 32768];
    const ushort* Bb = Ab + 16384;
    const bool more = (t + 1 < nt);

    // ---- P0: stage h0,h1(next) early + counted vmcnt; then issue Q1 reads ----
    if (more) {
      STAGE_HALF(t + 1, 0);
      STAGE_HALF(t + 1, 1);
      asm volatile("s_waitcnt vmcnt(4)" ::: "memory");   // tile t fully resident
    } else {
      asm volatile("s_waitcnt vmcnt(0)" ::: "memory");
    }
    BARRIER();
    RD_A4(af03, Ab, 0);
    RD_B2(bf01, Bb, 0);
    BARRIER();
    // ---- P1: read bf23 | MFMA Q1 ----
    RD_B2(bf23, Bb, 2);
    MFMA16(af03, bf01, 0, 0);
    if (more) STAGE_HALF(t + 1, 2);
    BARRIER();
    // ---- P2: read af47 | MFMA Q2 ----
    RD_A4(af47, Ab, 4);
    MFMA16(af03, bf23, 0, 2);
    if (more) STAGE_HALF(t + 1, 3);
    BARRIER();
    // ---- P3: drain LDS reads, pure MFMA Q3+Q4 ----
    asm volatile("s_waitcnt lgkmcnt(0)" ::: "memory");
    __builtin_amdgcn_sched_barrier(0);                   // rule #18
    MFMA16(af47, bf01, 4, 0);
    MFMA16(af47, bf23, 4, 2);
  }

  #pragma unroll
  for (int mi = 0; mi < 8; ++mi) {
    int grow_b = bm0 + wm * 128 + mi * 16 + fq * 4;
    #pragma unroll
    for (int ni = 0; ni < 4; ++ni) {
      int gcol = bn0 + wn * 64 + ni * 16 + fr;
      #pragma unroll
      for (int q = 0; q < 4; ++q) {
        int grow = grow_b + q;
        if constexpr (MODE == 0) {
          Cb[(size_t)grow * N + gcol] = f2bf(acc[mi][ni][q] + bias[gcol]);
        } else {
          Cb[((size_t)blockIdx.z * M + grow) * N + gcol] = f2bf(acc[mi][ni][q]);
        }
      }
    }
  }
}

// ---------------- reduce split-K partials + decoder epilogue ----------------
__global__ __launch_bounds__(256) void reduce_dec(
    const ushort* __restrict__ P, const float* __restrict__ b_pre,
    const float* __restrict__ stdv, const float* __restrict__ muv,
    float* __restrict__ out)
{
  int gid = blockIdx.x * 256 + threadIdx.x;
  size_t e0 = (size_t)gid * 4;
  int r = (int)(e0 >> 10), c = (int)(e0 & 1023);
  float sx = 0.f, sy = 0.f, sz = 0.f, sw = 0.f;
  #pragma unroll
  for (int ks = 0; ks < KSPLIT; ++ks) {
    ushort4 p = *(const ushort4*)&P[(size_t)ks * BATCH * IN_DIM + e0];
    sx += bf2f(p.x); sy += bf2f(p.y); sz += bf2f(p.z); sw += bf2f(p.w);
  }
  float4 bp = *(const float4*)&b_pre[c];
  float s = stdv[r], m = muv[r];
  float4 o;
  o.x = (sx + bp.x) * s + m;
  o.y = (sy + bp.y) * s + m;
  o.z = (sz + bp.z) * s + m;
  o.w = (sw + bp.w) * s + m;
  *(float4*)&out[e0] = o;
}

// ---------------- top-k v4: bf16 keys, exact bf16 thresholds, in-place dense A2 ---
__device__ __forceinline__ void scan_find(int* hist, int t, int K1, int K2,
                                          int* res, int* wsum)
{
  int lane = t & 63, w = t >> 6;
  int h[8];
  #pragma unroll
  for (int j = 0; j < 8; ++j) h[j] = hist[t * 8 + j];
  int p = 0;
  #pragma unroll
  for (int j = 0; j < 8; ++j) p += h[j];
  int v = p;
  #pragma unroll
  for (int off = 1; off < 64; off <<= 1) {
    int o = __shfl_down(v, off, 64);
    if (lane + off < 64) v += o;
  }
  if (lane == 0) wsum[w] = v;
  __syncthreads();
  int above_w = 0;
  for (int ww = w + 1; ww < 4; ++ww) above_w += wsum[ww];
  int incl = v + above_w;
  int E = incl - p;                // suffix strictly above this thread's bins
  int S[9];
  S[8] = E;
  #pragma unroll
  for (int j = 7; j >= 0; --j) S[j] = h[j] + S[j + 1];
  #pragma unroll
  for (int j = 0; j < 8; ++j) {
    if (S[j] >= K1 && S[j + 1] < K1) { res[0] = t * 8 + j; res[1] = S[j + 1]; }
    if (S[j] >= K2 && S[j + 1] < K2) { res[2] = t * 8 + j; res[3] = S[j + 1]; }
  }
  __syncthreads();
}

// Reads A2 row r (= pre_acts) into registers, then overwrites it IN PLACE with the
// dense aux row (strict-greater values, zeros, ties patched). Block-local: safe.
__global__ __launch_bounds__(256) void topk4_kernel(
    ushort* __restrict__ A2,
    int* __restrict__ midx, float* __restrict__ mval,
    int* __restrict__ fired)
{
  const int r = blockIdx.x, t = threadIdx.x;
  ushort* A2row = A2 + (size_t)r * HID;
  __shared__ int histA[NBIN];
  __shared__ int histC[32], histD[32];
  __shared__ int wsum[4];
  __shared__ int res[8];
  __shared__ int tidx64[TIE_CAP], tidx512[TIE_CAP];
  __shared__ int cm, ca, c64, c512;

  // 64 bf16 keys per thread (sortable u16: sign? ~u : u|0x8000)
  ushort key[64];
  const uint4* src = (const uint4*)A2row;
  #pragma unroll
  for (int c = 0; c < 8; ++c) {
    uint4 u = src[c * 256 + t];
    unsigned uu[4] = {u.x, u.y, u.z, u.w};
    #pragma unroll
    for (int p = 0; p < 4; ++p) {
      ushort lo = (ushort)(uu[p] & 0xFFFFu), hi = (ushort)(uu[p] >> 16);
      key[c * 8 + p * 2]     = (lo & 0x8000) ? (ushort)(lo ^ 0xFFFF) : (ushort)(lo | 0x8000);
      key[c * 8 + p * 2 + 1] = (hi & 0x8000) ? (ushort)(hi ^ 0xFFFF) : (ushort)(hi | 0x8000);
    }
  }
  #pragma unroll
  for (int j = 0; j < 8; ++j) histA[t * 8 + j] = 0;
  if (t < 32) { histC[t] = 0; histD[t] = 0; }
  if (t == 0) { cm = 0; ca = 0; c64 = 0; c512 = 0; }
  __syncthreads();

  // level 1: bins = key >> 5 (2048)
  #pragma unroll
  for (int q = 0; q < 64; ++q) atomicAdd(&histA[key[q] >> 5], 1);
  __syncthreads();
  scan_find(histA, t, KTOP, KAUX, res, wsum);
  const int B64 = res[0], above64 = res[1], B512 = res[2], above512 = res[3];

  // level 2: 32 sub-bins within each boundary bin -> exact bf16 threshold
  #pragma unroll
  for (int q = 0; q < 64; ++q) {
    int k = key[q];
    if ((k >> 5) == B64)  atomicAdd(&histC[k & 31], 1);
    if ((k >> 5) == B512) atomicAdd(&histD[k & 31], 1);
  }
  __syncthreads();
  if (t == 0) {
    int need = KTOP - above64, s = 0, sub = 31;
    for (int j = 31; j >= 0; --j) { s += histC[j]; if (s >= need) { sub = j; break; } }
    res[4] = (B64 << 5) | sub;
  }
  if (t == 64) {
    int need = KAUX - above512, s = 0, sub = 31;
    for (int j = 31; j >= 0; --j) { s += histD[j]; if (s >= need) { sub = j; break; } }
    res[6] = (B512 << 5) | sub;
  }
  __syncthreads();
  const ushort T64 = (ushort)res[4], T512 = (ushort)res[6];

  // output pass: main -> midx/mval/fired; aux -> dense in-place row write
  #pragma unroll
  for (int c = 0; c < 8; ++c) {
    ushort w8[8];
    #pragma unroll
    for (int j = 0; j < 8; ++j) {
      ushort k = key[c * 8 + j];
      int i = c * 2048 + t * 8 + j;
      ushort wv = 0;
      if (k > T512) {
        wv = (k > 0x8000) ? (ushort)(k & 0x7FFF) : (ushort)0;
        atomicAdd(&ca, 1);
      } else if (k == T512) {
        int p = atomicAdd(&c512, 1);
        if (p < TIE_CAP) tidx512[p] = i;
      }
      w8[j] = wv;
      if (k > T64) {
        int p = atomicAdd(&cm, 1);
        midx[(size_t)r * KTOP + p] = i;
        mval[(size_t)r * KTOP + p] = (k > 0x8000) ? bf2f((ushort)(k & 0x7FFF)) : 0.f;
        if (k > 0x8000) fired[i] = 1;
      } else if (k == T64) {
        int p = atomicAdd(&c64, 1);
        if (p < TIE_CAP) tidx64[p] = i;
      }
    }
    uint4 uu;
    uu.x = (unsigned)w8[0] | ((unsigned)w8[1] << 16);
    uu.y = (unsigned)w8[2] | ((unsigned)w8[3] << 16);
    uu.z = (unsigned)w8[4] | ((unsigned)w8[5] << 16);
    uu.w = (unsigned)w8[6] | ((unsigned)w8[7] << 16);
    *(uint4*)(A2row + c * 2048 + t * 8) = uu;
  }
  __syncthreads();

  if (t == 0) {   // fill main with ties (all same value), lowest index first
    int have = cm, ntc = c64 < TIE_CAP ? c64 : TIE_CAP, need = KTOP - have;
    float rv = (T64 > 0x8000) ? bf2f((ushort)(T64 & 0x7FFF)) : 0.f;
    for (int q = 0; q < need; ++q) {
      int best = 0x7FFFFFFF, bi = -1;
      for (int u = 0; u < ntc; ++u) if (tidx64[u] < best) { best = tidx64[u]; bi = u; }
      if (bi < 0) break;
      tidx64[bi] = 0x7FFFFFFF;
      midx[(size_t)r * KTOP + have + q] = best;
      mval[(size_t)r * KTOP + have + q] = rv;
      if (T64 > 0x8000) fired[best] = 1;
    }
  }
  if (t == 64) {  // patch aux ties into the dense row, lowest index first
    int have = ca, ntc = c512 < TIE_CAP ? c512 : TIE_CAP, need = KAUX - have;
    ushort rb = (T512 > 0x8000) ? (ushort)(T512 & 0x7FFF) : (ushort)0;
    for (int q = 0; q < need; ++q) {
      int best = 0x7FFFFFFF, bi = -1;
      for (int u = 0; u < ntc; ++u) if (tidx512[u] < best) { best = tidx512[u]; bi = u; }
      if (bi < 0) break;
      tidx512[bi] = 0x7FFFFFFF;
      A2row[best] = rb;
    }
  }
}

// ---------------- stats / num_dead ----------------
__global__ __launch_bounds__(256) void stats_kernel(
    const int* __restrict__ fired, const int* __restrict__ sln, float* __restrict__ nd_out)
{
  int t = threadIdx.x, c = 0;
  for (int j = t; j < HID; j += 256) {
    int dead = (fired[j] == 0) ? 1 : 0;
    int stats = sln[j] * dead + 1;
    if ((float)stats > (2000.0f / 4096.0f)) c++;
  }
  c = block_sum_i(c);
  if (t == 0) nd_out[0] = (float)c;
}

// ---------------- main decode: sparse gather of bf16 w_dec, 2 rows / block -------
__global__ __launch_bounds__(512) void decode_main(
    const int* __restrict__ midx, const float* __restrict__ mval,
    const ushort* __restrict__ wdecB, const float* __restrict__ b_pre,
    const float* __restrict__ stdv, const float* __restrict__ muv,
    float* __restrict__ out)
{
  int w = threadIdx.x >> 8, t = threadIdx.x & 255;
  int r = blockIdx.x * 2 + w;
  __shared__ int sj[2][KTOP];
  __shared__ float sv[2][KTOP];
  if (t < KTOP) {
    sj[w][t] = midx[(size_t)r * KTOP + t];
    sv[w][t] = mval[(size_t)r * KTOP + t];
  }
  __syncthreads();
  float ax = 0.f, ay = 0.f, az = 0.f, aw = 0.f;
  #pragma unroll 8
  for (int i = 0; i < KTOP; ++i) {
    float v = sv[w][i];
    ushort4 wv = *(const ushort4*)(wdecB + (size_t)sj[w][i] * IN_DIM + t * 4);
    ax += v * bf2f(wv.x); ay += v * bf2f(wv.y);
    az += v * bf2f(wv.z); aw += v * bf2f(wv.w);
  }
  float4 bp = ((const float4*)b_pre)[t];
  float s = stdv[r], m = muv[r];
  float4 o;
  o.x = (ax + bp.x) * s + m;
  o.y = (ay + bp.y) * s + m;
  o.z = (az + bp.z) * s + m;
  o.w = (aw + bp.w) * s + m;
  ((float4*)(out + (size_t)r * IN_DIM))[t] = o;
}

__global__ void diag_kernel(float* p, float v) { p[0] = v; }

// ---------------- launch ----------------
extern "C" void kernel_launch(void* const* d_in, const int* in_sizes, int n_in,
                              void* d_out, int out_size, void* d_ws, size_t ws_size,
                              hipStream_t stream)
{
  const float* x     = (const float*)d_in[0];
  const float* w_enc = (const float*)d_in[1];
  const float* w_dec = (const float*)d_in[2];
  const float* b_enc = (const float*)d_in[3];
  const float* b_pre = (const float*)d_in[4];
  const int*   sln   = (const int*)d_in[5];

  float* out0 = (float*)d_out;                          // recons [4096][1024]
  float* out1 = out0 + (size_t)BATCH * IN_DIM;          // aux_recons
  float* out2 = out0 + 2 * (size_t)BATCH * IN_DIM;      // num_dead (as f32)

  char* ws = (char*)d_ws;
  size_t off = 0;
  auto take = [&](size_t bytes) { char* p = ws + off; off += (bytes + 255) & ~(size_t)255; return p; };

  // A2 (128 MB): encoder writes full-batch bf16 pre_acts here; topk4 converts each
  // row IN PLACE to the dense aux matrix.
  ushort* A2       = (ushort*)take((size_t)BATCH * HID * 2);
  // wencT (32 MB) is dead after the encoder -> reused as split-K partials (KSPLIT=4)
  ushort* wencT    = (ushort*)take((size_t)HID * IN_DIM * 2);
  ushort* part     = wencT;
  ushort* wdecB    = (ushort*)take((size_t)HID * IN_DIM * 2);
  ushort* wdecT    = (ushort*)take((size_t)HID * IN_DIM * 2);
  ushort* xh       = (ushort*)take((size_t)BATCH * IN_DIM * 2);
  float*  mu       = (float*)take(BATCH * 4);
  float*  stdv     = (float*)take(BATCH * 4);
  int*    midx     = (int*)take((size_t)BATCH * KTOP * 4);
  float*  mval     = (float*)take((size_t)BATCH * KTOP * 4);
  int*    fired    = (int*)take(HID * 4);

  if (ws_size < off) {  // diagnostic: report actual ws_size through num_dead slot
    diag_kernel<<<1, 1, 0, stream>>>(out2, (float)ws_size);
    return;
  }

  // fused prologue: LN + fired-zero + both weight transposes in one launch
  prep_kernel<<<BATCH + 2 * 16384, 256, 0, stream>>>(
      x, b_pre, xh, mu, stdv, w_enc, wencT, w_dec, wdecT, wdecB, fired);

  // full-batch encoder: grid (64,16) = 1024 blocks
  gemm256<0><<<dim3(HID / 256, BATCH / 256, 1), 512, 0, stream>>>(
      xh, wencT, A2, b_enc, BATCH, HID, IN_DIM, IN_DIM);
  // full-batch in-place top-k (pre row -> dense aux row)
  topk4_kernel<<<BATCH, 256, 0, stream>>>(A2, midx, mval, fired);
  stats_kernel<<<1, 256, 0, stream>>>(fired, sln, out2);

  // main decode: consumes wdecB (untouched later; part aliases wencT only)
  decode_main<<<BATCH / 2, 512, 0, stream>>>(midx, mval, wdecB, b_pre, stdv, mu, out0);

  gemm256<1><<<dim3(IN_DIM / 256, BATCH / 256, KSPLIT), 512, 0, stream>>>(
      A2, wdecT, part, nullptr, BATCH, IN_DIM, HID, HID / KSPLIT);
  reduce_dec<<<(BATCH * IN_DIM) / 1024, 256, 0, stream>>>(part, b_pre, stdv, mu, out1);
}

// Round 14
// 492.075 us; speedup vs baseline: 1.0535x; 1.0445x over previous
//
#include <hip/hip_runtime.h>

#define BATCH 4096
#define IN_DIM 1024
#define HID 16384
#define KTOP 64
#define KAUX 512
#define KSPLIT 4
#define LN_EPS 1e-5f
#define TIE_CAP 768
#define NBIN 2048

typedef short s16x8 __attribute__((ext_vector_type(8)));
typedef float f32x4 __attribute__((ext_vector_type(4)));

__device__ __forceinline__ ushort f2bf(float f) {
  unsigned u = __float_as_uint(f);
  u += 0x7FFFu + ((u >> 16) & 1u);   // RNE
  return (ushort)(u >> 16);
}
__device__ __forceinline__ float bf2f(ushort h) {
  return __uint_as_float(((unsigned)h) << 16);
}

__device__ __forceinline__ void gl_lds16(const void* g, void* l) {
  __builtin_amdgcn_global_load_lds(
      (const __attribute__((address_space(1))) unsigned*)g,
      (__attribute__((address_space(3))) unsigned*)l, 16, 0, 0);
}

#define BARRIER() do { __builtin_amdgcn_s_barrier(); asm volatile("" ::: "memory"); } while (0)

__device__ __forceinline__ float block_sum_f(float v) {
  __shared__ float redf[4];
  for (int o = 32; o > 0; o >>= 1) v += __shfl_down(v, o, 64);
  int lane = threadIdx.x & 63, w = threadIdx.x >> 6;
  if (lane == 0) redf[w] = v;
  __syncthreads();
  float t = (redf[0] + redf[1]) + (redf[2] + redf[3]);
  __syncthreads();
  return t;
}

__device__ __forceinline__ int block_sum_i(int v) {
  __shared__ int redi[4];
  for (int o = 32; o > 0; o >>= 1) v += __shfl_down(v, o, 64);
  int lane = threadIdx.x & 63, w = threadIdx.x >> 6;
  if (lane == 0) redi[w] = v;
  __syncthreads();
  int t = (redi[0] + redi[1]) + (redi[2] + redi[3]);
  __syncthreads();
  return t;
}

// ---------------- fused prologue -----------------------------------------------
// blocks [0,4096):          LayerNorm row (blocks 0..15 also zero `fired`)
// blocks [4096,20480):      transpose w_enc -> wencT (bf16 [HID][IN_DIM])
// blocks [20480,36864):     transpose w_dec -> wdecT + row-major bf16 wdecB
__global__ __launch_bounds__(256) void prep_kernel(
    const float* __restrict__ x, const float* __restrict__ b_pre,
    ushort* __restrict__ xh, float* __restrict__ mu, float* __restrict__ stdv,
    const float* __restrict__ w_enc, ushort* __restrict__ wencT,
    const float* __restrict__ w_dec, ushort* __restrict__ wdecT,
    ushort* __restrict__ wdecB, int* __restrict__ fired)
{
  __shared__ float tile[32][33];
  int id = blockIdx.x;
  int t = threadIdx.x;

  if (id < BATCH) {
    // ---- LayerNorm ----
    if (id < 16) *(int4*)&fired[id * 1024 + t * 4] = make_int4(0, 0, 0, 0);
    int r = id;
    float4 v = ((const float4*)(x + (size_t)r * IN_DIM))[t];
    float s = (v.x + v.y) + (v.z + v.w);
    float mean = block_sum_f(s) * (1.0f / IN_DIM);
    float dx = v.x - mean, dy = v.y - mean, dz = v.z - mean, dw = v.w - mean;
    float ss = (dx*dx + dy*dy) + (dz*dz + dw*dw);
    float var = block_sum_f(ss) * (1.0f / (IN_DIM - 1));   // ddof = 1
    float sd = sqrtf(var);
    float inv = 1.0f / (sd + LN_EPS);
    float4 bp = ((const float4*)b_pre)[t];
    ushort h0 = f2bf(dx*inv - bp.x), h1 = f2bf(dy*inv - bp.y);
    ushort h2 = f2bf(dz*inv - bp.z), h3 = f2bf(dw*inv - bp.w);
    *(ushort4*)(xh + (size_t)r * IN_DIM + t * 4) = make_ushort4(h0, h1, h2, h3);
    if (t == 0) { mu[r] = mean; stdv[r] = sd; }
    return;
  }
  id -= BATCH;

  const float* in; ushort* oh; ushort* orow; int R, C, bx, by;
  if (id < 16384) {
    in = w_enc; oh = wencT; orow = nullptr; R = IN_DIM; C = HID;
    bx = id & 511; by = id >> 9;
  } else {
    id -= 16384;
    in = w_dec; oh = wdecT; orow = wdecB; R = HID; C = IN_DIM;
    bx = id & 31; by = id >> 5;
  }
  int c0 = bx * 32, r0 = by * 32;
  int col = t & 31, rbase = t >> 5;
  #pragma unroll
  for (int rep = 0; rep < 4; ++rep) {
    int rr = rbase + rep * 8;
    float v = in[(size_t)(r0 + rr) * C + c0 + col];
    tile[rr][col] = v;
    if (orow) orow[(size_t)(r0 + rr) * C + c0 + col] = f2bf(v);
  }
  __syncthreads();
  int j = t & 31, ibase = t >> 5;
  #pragma unroll
  for (int rep = 0; rep < 4; ++rep) {
    int i = ibase + rep * 8;
    oh[(size_t)(c0 + i) * R + r0 + j] = f2bf(tile[j][i]);
  }
}

// ---- frag-read / MFMA helpers (compile-time indices only — rule #20) ----
#define RD_A4(DST, PA, MI0)                                                     \
  _Pragma("unroll")                                                             \
  for (int ks = 0; ks < 2; ++ks)                                                \
    _Pragma("unroll")                                                           \
    for (int i = 0; i < 4; ++i)                                                 \
      DST[ks][i] = *(const s16x8*)&PA[(wm * 128 + ((MI0) + i) * 16 + fr) * 64 + \
                                      (((ks * 4 + fq) ^ axr) * 8)];

#define RD_B2(DST, PB, NI0)                                                     \
  _Pragma("unroll")                                                             \
  for (int ks = 0; ks < 2; ++ks)                                                \
    _Pragma("unroll")                                                           \
    for (int n = 0; n < 2; ++n)                                                 \
      DST[ks][n] = *(const s16x8*)&PB[(wn * 64 + ((NI0) + n) * 16 + fr) * 64 +  \
                                      (((ks * 4 + fq) ^ axr) * 8)];

#define MFMA16(AF, BF, MI0, NI0)                                                \
  __builtin_amdgcn_s_setprio(1);                                                \
  _Pragma("unroll")                                                             \
  for (int ks = 0; ks < 2; ++ks)                                                \
    _Pragma("unroll")                                                           \
    for (int i = 0; i < 4; ++i)                                                 \
      _Pragma("unroll")                                                         \
      for (int n = 0; n < 2; ++n)                                               \
        acc[(MI0) + i][(NI0) + n] = __builtin_amdgcn_mfma_f32_16x16x32_bf16(    \
            AF[ks][i], BF[ks][n], acc[(MI0) + i][(NI0) + n], 0, 0, 0);          \
  __builtin_amdgcn_s_setprio(0);

// ---------------- GEMM C = A @ B^T, 256x256, 8-phase windows + counted vmcnt ------
// LDS: 2 buf x (A 256x64 | B 256x64) bf16 = 128 KiB. T2 both-sides XOR swizzle.
// MODE 0: Cb bf16 = f2bf(acc + bias[n])   (encoder; 2D-XCD map: XCD owns 8 bn x all bm)
// MODE 1: Cb bf16 partial (split-K via z)  (decoder)
template<int MODE>
__global__ __launch_bounds__(512, 2) void gemm256(
    const ushort* __restrict__ A, const ushort* __restrict__ B,
    ushort* __restrict__ Cb, const float* __restrict__ bias,
    int M, int N, int K, int kchunk)
{
  __shared__ ushort lds[2 * 2 * 256 * 64];

  const int tid = threadIdx.x;
  const int w = tid >> 6, lane = tid & 63;
  const int fr = lane & 15, fq = lane >> 4;
  const int wm = w >> 2, wn = w & 3;
  const int axr = fr & 7;

  int bn0, bm0;
  const int flat = blockIdx.y * gridDim.x + blockIdx.x;
  if constexpr (MODE == 0) {
    // XCD x (= flat&7) owns bn panels [8x,8x+8) x all bm tiles.
    const int x = flat & 7, k = flat >> 3;
    bn0 = (x * 8 + (k & 7)) * 256;
    bm0 = (k >> 3) * 256;
  } else {
    const int gx = gridDim.x, nwg = gx * gridDim.y;   // %8==0
    const int cpx = nwg >> 3;
    const int sw = (flat & 7) * cpx + (flat >> 3);
    bn0 = (sw % gx) * 256; bm0 = (sw / gx) * 256;
  }
  const int kbeg = blockIdx.z * kchunk;

  const int srow = tid >> 3, sslot = tid & 7;

  // stage half h of K-tile kt: h 0,1 = A rows [0,128)/[128,256); h 2,3 = B same.
  auto STAGE_HALF = [&](int kt, int h) {
    const int k0 = kbeg + (kt << 6);
    const int lb = (kt & 1) * 32768 + (h >> 1) * 16384;
    #pragma unroll
    for (int q = 0; q < 2; ++q) {
      int row = (h & 1) * 128 + q * 64 + srow;
      int gcol = (sslot ^ (row & 7)) * 8;
      const ushort* src = (h < 2) ? (A + (size_t)(bm0 + row) * K)
                                  : (B + (size_t)(bn0 + row) * K);
      gl_lds16(src + k0 + gcol, &lds[lb + row * 64 + sslot * 8]);
    }
  };

  f32x4 acc[8][4] = {};
  const int nt = kchunk >> 6;

  #pragma unroll
  for (int h = 0; h < 4; ++h) STAGE_HALF(0, h);

  s16x8 af03[2][4], af47[2][4], bf01[2][2], bf23[2][2];

  for (int t = 0; t < nt; ++t) {
    const ushort* Ab = &lds[(t & 1) * 32768];
    const ushort* Bb = Ab + 16384;
    const bool more = (t + 1 < nt);

    // ---- P0: stage h0,h1(next) early + counted vmcnt; then issue Q1 reads ----
    if (more) {
      STAGE_HALF(t + 1, 0);
      STAGE_HALF(t + 1, 1);
      asm volatile("s_waitcnt vmcnt(4)" ::: "memory");   // tile t fully resident
    } else {
      asm volatile("s_waitcnt vmcnt(0)" ::: "memory");
    }
    BARRIER();
    RD_A4(af03, Ab, 0);
    RD_B2(bf01, Bb, 0);
    BARRIER();
    // ---- P1: read bf23 | MFMA Q1 ----
    RD_B2(bf23, Bb, 2);
    MFMA16(af03, bf01, 0, 0);
    if (more) STAGE_HALF(t + 1, 2);
    BARRIER();
    // ---- P2: read af47 | MFMA Q2 ----
    RD_A4(af47, Ab, 4);
    MFMA16(af03, bf23, 0, 2);
    if (more) STAGE_HALF(t + 1, 3);
    BARRIER();
    // ---- P3: drain LDS reads, pure MFMA Q3+Q4 ----
    asm volatile("s_waitcnt lgkmcnt(0)" ::: "memory");
    __builtin_amdgcn_sched_barrier(0);                   // rule #18
    MFMA16(af47, bf01, 4, 0);
    MFMA16(af47, bf23, 4, 2);
  }

  #pragma unroll
  for (int mi = 0; mi < 8; ++mi) {
    int grow_b = bm0 + wm * 128 + mi * 16 + fq * 4;
    #pragma unroll
    for (int ni = 0; ni < 4; ++ni) {
      int gcol = bn0 + wn * 64 + ni * 16 + fr;
      #pragma unroll
      for (int q = 0; q < 4; ++q) {
        int grow = grow_b + q;
        if constexpr (MODE == 0) {
          Cb[(size_t)grow * N + gcol] = f2bf(acc[mi][ni][q] + bias[gcol]);
        } else {
          Cb[((size_t)blockIdx.z * M + grow) * N + gcol] = f2bf(acc[mi][ni][q]);
        }
      }
    }
  }
}

// ---------------- top-k v4: bf16 keys, exact bf16 thresholds, in-place dense A2 ---
__device__ __forceinline__ void scan_find(int* hist, int t, int K1, int K2,
                                          int* res, int* wsum)
{
  int lane = t & 63, w = t >> 6;
  int h[8];
  #pragma unroll
  for (int j = 0; j < 8; ++j) h[j] = hist[t * 8 + j];
  int p = 0;
  #pragma unroll
  for (int j = 0; j < 8; ++j) p += h[j];
  int v = p;
  #pragma unroll
  for (int off = 1; off < 64; off <<= 1) {
    int o = __shfl_down(v, off, 64);
    if (lane + off < 64) v += o;
  }
  if (lane == 0) wsum[w] = v;
  __syncthreads();
  int above_w = 0;
  for (int ww = w + 1; ww < 4; ++ww) above_w += wsum[ww];
  int incl = v + above_w;
  int E = incl - p;                // suffix strictly above this thread's bins
  int S[9];
  S[8] = E;
  #pragma unroll
  for (int j = 7; j >= 0; --j) S[j] = h[j] + S[j + 1];
  #pragma unroll
  for (int j = 0; j < 8; ++j) {
    if (S[j] >= K1 && S[j + 1] < K1) { res[0] = t * 8 + j; res[1] = S[j + 1]; }
    if (S[j] >= K2 && S[j + 1] < K2) { res[2] = t * 8 + j; res[3] = S[j + 1]; }
  }
  __syncthreads();
}

// Reads A2 row r (= pre_acts) into registers, then overwrites it IN PLACE with the
// dense aux row (strict-greater values, zeros, ties patched). Block-local: safe.
__global__ __launch_bounds__(256) void topk4_kernel(
    ushort* __restrict__ A2,
    int* __restrict__ midx, float* __restrict__ mval,
    int* __restrict__ fired)
{
  const int r = blockIdx.x, t = threadIdx.x;
  ushort* A2row = A2 + (size_t)r * HID;
  __shared__ int histA[NBIN];
  __shared__ int histC[32], histD[32];
  __shared__ int wsum[4];
  __shared__ int res[8];
  __shared__ int tidx64[TIE_CAP], tidx512[TIE_CAP];
  __shared__ int cm, ca, c64, c512;

  // 64 bf16 keys per thread (sortable u16: sign? ~u : u|0x8000)
  ushort key[64];
  const uint4* src = (const uint4*)A2row;
  #pragma unroll
  for (int c = 0; c < 8; ++c) {
    uint4 u = src[c * 256 + t];
    unsigned uu[4] = {u.x, u.y, u.z, u.w};
    #pragma unroll
    for (int p = 0; p < 4; ++p) {
      ushort lo = (ushort)(uu[p] & 0xFFFFu), hi = (ushort)(uu[p] >> 16);
      key[c * 8 + p * 2]     = (lo & 0x8000) ? (ushort)(lo ^ 0xFFFF) : (ushort)(lo | 0x8000);
      key[c * 8 + p * 2 + 1] = (hi & 0x8000) ? (ushort)(hi ^ 0xFFFF) : (ushort)(hi | 0x8000);
    }
  }
  #pragma unroll
  for (int j = 0; j < 8; ++j) histA[t * 8 + j] = 0;
  if (t < 32) { histC[t] = 0; histD[t] = 0; }
  if (t == 0) { cm = 0; ca = 0; c64 = 0; c512 = 0; }
  __syncthreads();

  // level 1: bins = key >> 5 (2048)
  #pragma unroll
  for (int q = 0; q < 64; ++q) atomicAdd(&histA[key[q] >> 5], 1);
  __syncthreads();
  scan_find(histA, t, KTOP, KAUX, res, wsum);
  const int B64 = res[0], above64 = res[1], B512 = res[2], above512 = res[3];

  // level 2: 32 sub-bins within each boundary bin -> exact bf16 threshold
  #pragma unroll
  for (int q = 0; q < 64; ++q) {
    int k = key[q];
    if ((k >> 5) == B64)  atomicAdd(&histC[k & 31], 1);
    if ((k >> 5) == B512) atomicAdd(&histD[k & 31], 1);
  }
  __syncthreads();
  if (t == 0) {
    int need = KTOP - above64, s = 0, sub = 31;
    for (int j = 31; j >= 0; --j) { s += histC[j]; if (s >= need) { sub = j; break; } }
    res[4] = (B64 << 5) | sub;
  }
  if (t == 64) {
    int need = KAUX - above512, s = 0, sub = 31;
    for (int j = 31; j >= 0; --j) { s += histD[j]; if (s >= need) { sub = j; break; } }
    res[6] = (B512 << 5) | sub;
  }
  __syncthreads();
  const ushort T64 = (ushort)res[4], T512 = (ushort)res[6];

  // output pass: main -> midx/mval/fired; aux -> dense in-place row write
  #pragma unroll
  for (int c = 0; c < 8; ++c) {
    ushort w8[8];
    #pragma unroll
    for (int j = 0; j < 8; ++j) {
      ushort k = key[c * 8 + j];
      int i = c * 2048 + t * 8 + j;
      ushort wv = 0;
      if (k > T512) {
        wv = (k > 0x8000) ? (ushort)(k & 0x7FFF) : (ushort)0;
        atomicAdd(&ca, 1);
      } else if (k == T512) {
        int p = atomicAdd(&c512, 1);
        if (p < TIE_CAP) tidx512[p] = i;
      }
      w8[j] = wv;
      if (k > T64) {
        int p = atomicAdd(&cm, 1);
        midx[(size_t)r * KTOP + p] = i;
        mval[(size_t)r * KTOP + p] = (k > 0x8000) ? bf2f((ushort)(k & 0x7FFF)) : 0.f;
        if (k > 0x8000) fired[i] = 1;
      } else if (k == T64) {
        int p = atomicAdd(&c64, 1);
        if (p < TIE_CAP) tidx64[p] = i;
      }
    }
    uint4 uu;
    uu.x = (unsigned)w8[0] | ((unsigned)w8[1] << 16);
    uu.y = (unsigned)w8[2] | ((unsigned)w8[3] << 16);
    uu.z = (unsigned)w8[4] | ((unsigned)w8[5] << 16);
    uu.w = (unsigned)w8[6] | ((unsigned)w8[7] << 16);
    *(uint4*)(A2row + c * 2048 + t * 8) = uu;
  }
  __syncthreads();

  if (t == 0) {   // fill main with ties (all same value), lowest index first
    int have = cm, ntc = c64 < TIE_CAP ? c64 : TIE_CAP, need = KTOP - have;
    float rv = (T64 > 0x8000) ? bf2f((ushort)(T64 & 0x7FFF)) : 0.f;
    for (int q = 0; q < need; ++q) {
      int best = 0x7FFFFFFF, bi = -1;
      for (int u = 0; u < ntc; ++u) if (tidx64[u] < best) { best = tidx64[u]; bi = u; }
      if (bi < 0) break;
      tidx64[bi] = 0x7FFFFFFF;
      midx[(size_t)r * KTOP + have + q] = best;
      mval[(size_t)r * KTOP + have + q] = rv;
      if (T64 > 0x8000) fired[best] = 1;
    }
  }
  if (t == 64) {  // patch aux ties into the dense row, lowest index first
    int have = ca, ntc = c512 < TIE_CAP ? c512 : TIE_CAP, need = KAUX - have;
    ushort rb = (T512 > 0x8000) ? (ushort)(T512 & 0x7FFF) : (ushort)0;
    for (int q = 0; q < need; ++q) {
      int best = 0x7FFFFFFF, bi = -1;
      for (int u = 0; u < ntc; ++u) if (tidx512[u] < best) { best = tidx512[u]; bi = u; }
      if (bi < 0) break;
      tidx512[bi] = 0x7FFFFFFF;
      A2row[best] = rb;
    }
  }
}

// ---------------- fused epilogue: out0 gather + out1 split-K reduce + num_dead ----
// block r: row r of BOTH outputs. Block 0 additionally computes num_dead.
__global__ __launch_bounds__(256) void epilogue_kernel(
    const int* __restrict__ midx, const float* __restrict__ mval,
    const ushort* __restrict__ wdecB, const ushort* __restrict__ P,
    const float* __restrict__ b_pre, const float* __restrict__ stdv,
    const float* __restrict__ muv,
    const int* __restrict__ fired, const int* __restrict__ sln,
    float* __restrict__ out0, float* __restrict__ out1, float* __restrict__ out2)
{
  int r = blockIdx.x, t = threadIdx.x;
  __shared__ int sj[KTOP];
  __shared__ float sv[KTOP];
  if (t < KTOP) { sj[t] = midx[(size_t)r * KTOP + t]; sv[t] = mval[(size_t)r * KTOP + t]; }
  __syncthreads();

  size_t e0 = (size_t)r * IN_DIM + t * 4;
  float4 bp = ((const float4*)b_pre)[t];
  float s = stdv[r], m = muv[r];

  // out0: sparse gather of bf16 w_dec rows (same order as previous decode_main)
  float ax = 0.f, ay = 0.f, az = 0.f, aw = 0.f;
  #pragma unroll 8
  for (int i = 0; i < KTOP; ++i) {
    float v = sv[i];
    ushort4 wv = *(const ushort4*)(wdecB + (size_t)sj[i] * IN_DIM + t * 4);
    ax += v * bf2f(wv.x); ay += v * bf2f(wv.y);
    az += v * bf2f(wv.z); aw += v * bf2f(wv.w);
  }
  float4 o0;
  o0.x = (ax + bp.x) * s + m;
  o0.y = (ay + bp.y) * s + m;
  o0.z = (az + bp.z) * s + m;
  o0.w = (aw + bp.w) * s + m;
  *(float4*)&out0[e0] = o0;

  // out1: split-K partial reduce (same order as previous reduce_dec)
  float sx = 0.f, sy = 0.f, sz = 0.f, sw = 0.f;
  #pragma unroll
  for (int ks = 0; ks < KSPLIT; ++ks) {
    ushort4 p = *(const ushort4*)&P[(size_t)ks * BATCH * IN_DIM + e0];
    sx += bf2f(p.x); sy += bf2f(p.y); sz += bf2f(p.z); sw += bf2f(p.w);
  }
  float4 o1;
  o1.x = (sx + bp.x) * s + m;
  o1.y = (sy + bp.y) * s + m;
  o1.z = (sz + bp.z) * s + m;
  o1.w = (sw + bp.w) * s + m;
  *(float4*)&out1[e0] = o1;

  // num_dead (block 0 only)
  if (r == 0) {
    int c = 0;
    for (int j = t; j < HID; j += 256) {
      int dead = (fired[j] == 0) ? 1 : 0;
      int stats = sln[j] * dead + 1;
      if ((float)stats > (2000.0f / 4096.0f)) c++;
    }
    c = block_sum_i(c);
    if (t == 0) out2[0] = (float)c;
  }
}

__global__ void diag_kernel(float* p, float v) { p[0] = v; }

// ---------------- launch ----------------
extern "C" void kernel_launch(void* const* d_in, const int* in_sizes, int n_in,
                              void* d_out, int out_size, void* d_ws, size_t ws_size,
                              hipStream_t stream)
{
  const float* x     = (const float*)d_in[0];
  const float* w_enc = (const float*)d_in[1];
  const float* w_dec = (const float*)d_in[2];
  const float* b_enc = (const float*)d_in[3];
  const float* b_pre = (const float*)d_in[4];
  const int*   sln   = (const int*)d_in[5];

  float* out0 = (float*)d_out;                          // recons [4096][1024]
  float* out1 = out0 + (size_t)BATCH * IN_DIM;          // aux_recons
  float* out2 = out0 + 2 * (size_t)BATCH * IN_DIM;      // num_dead (as f32)

  char* ws = (char*)d_ws;
  size_t off = 0;
  auto take = [&](size_t bytes) { char* p = ws + off; off += (bytes + 255) & ~(size_t)255; return p; };

  // A2 (128 MB): encoder writes full-batch bf16 pre_acts here; topk4 converts each
  // row IN PLACE to the dense aux matrix.
  ushort* A2       = (ushort*)take((size_t)BATCH * HID * 2);
  // wencT (32 MB) is dead after the encoder -> reused as split-K partials (KSPLIT=4)
  ushort* wencT    = (ushort*)take((size_t)HID * IN_DIM * 2);
  ushort* part     = wencT;
  ushort* wdecB    = (ushort*)take((size_t)HID * IN_DIM * 2);
  ushort* wdecT    = (ushort*)take((size_t)HID * IN_DIM * 2);
  ushort* xh       = (ushort*)take((size_t)BATCH * IN_DIM * 2);
  float*  mu       = (float*)take(BATCH * 4);
  float*  stdv     = (float*)take(BATCH * 4);
  int*    midx     = (int*)take((size_t)BATCH * KTOP * 4);
  float*  mval     = (float*)take((size_t)BATCH * KTOP * 4);
  int*    fired    = (int*)take(HID * 4);

  if (ws_size < off) {  // diagnostic: report actual ws_size through num_dead slot
    diag_kernel<<<1, 1, 0, stream>>>(out2, (float)ws_size);
    return;
  }

  // fused prologue: LN + fired-zero + both weight transposes in one launch
  prep_kernel<<<BATCH + 2 * 16384, 256, 0, stream>>>(
      x, b_pre, xh, mu, stdv, w_enc, wencT, w_dec, wdecT, wdecB, fired);

  // full-batch encoder: grid (64,16) = 1024 blocks
  gemm256<0><<<dim3(HID / 256, BATCH / 256, 1), 512, 0, stream>>>(
      xh, wencT, A2, b_enc, BATCH, HID, IN_DIM, IN_DIM);
  // full-batch in-place top-k (pre row -> dense aux row)
  topk4_kernel<<<BATCH, 256, 0, stream>>>(A2, midx, mval, fired);

  // aux decode GEMM (split-K partials into part)
  gemm256<1><<<dim3(IN_DIM / 256, BATCH / 256, KSPLIT), 512, 0, stream>>>(
      A2, wdecT, part, nullptr, BATCH, IN_DIM, HID, HID / KSPLIT);

  // fused epilogue: out0 gather + out1 reduce + num_dead
  epilogue_kernel<<<BATCH, 256, 0, stream>>>(
      midx, mval, wdecB, part, b_pre, stdv, mu, fired, sln, out0, out1, out2);
}